// Round 4
// baseline (276.050 us; speedup 1.0000x reference)
//
#include <hip/hip_runtime.h>
#include <hip/hip_bf16.h>
#include <stdint.h>

#define HW   4096
#define CIN  256
#define CR   32
#define COUT 560   // 32 + 528 pair channels

// Kernel 1: z = relu(bn(conv1x1(x))), fp32 in/accum, z stored fp32 in ws.
// Block = 256 thr = 4 waves. Wave og handles out-channels og*8..og*8+7.
// Lane handles 4 consecutive pixels (float4). Block covers 256 pixels.
__global__ __launch_bounds__(256) void k_conv1x1(
    const float* __restrict__ x,
    const float* __restrict__ wr,
    const float* __restrict__ gamma,
    const float* __restrict__ beta,
    const float* __restrict__ mean,
    const float* __restrict__ var,
    float* __restrict__ z)
{
    __shared__ __align__(16) float wlds[CR * CIN];   // 32 KB fp32 [o][i]
    const int tid = threadIdx.x;
    {
        const float4* wr4 = (const float4*)wr;
        float4* wl4 = (float4*)wlds;
        #pragma unroll
        for (int k = 0; k < 8; ++k) wl4[tid + k * 256] = wr4[tid + k * 256];
    }
    __syncthreads();

    const int og   = tid >> 6;     // 0..3 -> out-channel group
    const int lane = tid & 63;
    const int g0 = blockIdx.x * 256 + lane * 4;   // global pixel index (x4)
    const int b = g0 >> 12;
    const int p = g0 & 4095;
    const float* xb = x + ((((size_t)b) * CIN) << 12) + p;
    const int ob = og * 8;

    float4 acc[8];
    #pragma unroll
    for (int o = 0; o < 8; ++o) acc[o] = make_float4(0.f, 0.f, 0.f, 0.f);

    for (int i4 = 0; i4 < 64; ++i4) {
        float4 xv0 = *(const float4*)(xb + ((size_t)(i4 * 4 + 0) << 12));
        float4 xv1 = *(const float4*)(xb + ((size_t)(i4 * 4 + 1) << 12));
        float4 xv2 = *(const float4*)(xb + ((size_t)(i4 * 4 + 2) << 12));
        float4 xv3 = *(const float4*)(xb + ((size_t)(i4 * 4 + 3) << 12));
        #pragma unroll
        for (int o = 0; o < 8; ++o) {
            float4 wv = *(const float4*)&wlds[(ob + o) * 256 + i4 * 4]; // broadcast b128
            acc[o].x = fmaf(xv0.x, wv.x, acc[o].x);
            acc[o].y = fmaf(xv0.y, wv.x, acc[o].y);
            acc[o].z = fmaf(xv0.z, wv.x, acc[o].z);
            acc[o].w = fmaf(xv0.w, wv.x, acc[o].w);
            acc[o].x = fmaf(xv1.x, wv.y, acc[o].x);
            acc[o].y = fmaf(xv1.y, wv.y, acc[o].y);
            acc[o].z = fmaf(xv1.z, wv.y, acc[o].z);
            acc[o].w = fmaf(xv1.w, wv.y, acc[o].w);
            acc[o].x = fmaf(xv2.x, wv.z, acc[o].x);
            acc[o].y = fmaf(xv2.y, wv.z, acc[o].y);
            acc[o].z = fmaf(xv2.z, wv.z, acc[o].z);
            acc[o].w = fmaf(xv2.w, wv.z, acc[o].w);
            acc[o].x = fmaf(xv3.x, wv.w, acc[o].x);
            acc[o].y = fmaf(xv3.y, wv.w, acc[o].y);
            acc[o].z = fmaf(xv3.z, wv.w, acc[o].z);
            acc[o].w = fmaf(xv3.w, wv.w, acc[o].w);
        }
    }

    #pragma unroll
    for (int o = 0; o < 8; ++o) {
        const int oc = ob + o;
        const float inv = gamma[oc] / sqrtf(var[oc] + 1e-5f);
        const float bia = beta[oc] - mean[oc] * inv;
        float4 r;
        r.x = fmaxf(fmaf(acc[o].x, inv, bia), 0.f);
        r.y = fmaxf(fmaf(acc[o].y, inv, bia), 0.f);
        r.z = fmaxf(fmaf(acc[o].z, inv, bia), 0.f);
        r.w = fmaxf(fmaf(acc[o].w, inv, bia), 0.f);
        *(float4*)(z + ((((size_t)b) * CR + oc) << 12) + p) = r;
    }
}

// Kernel 2: depthwise 3x3 (SAME) * scale, dual L2-normalize, 32 + 528 fp32 outputs.
// 1 thread per pixel; grid 256 x 256.
__global__ __launch_bounds__(256) void k_twist(
    const float* __restrict__ z,
    const float* __restrict__ dww,
    const float* __restrict__ scl,
    float* __restrict__ out)
{
    __shared__ float dml[CR * 9];
    __shared__ float sc[CR];
    const int tid = threadIdx.x;
    // CR*9 = 288 > 256 threads: must stride
    for (int t = tid; t < CR * 9; t += 256) dml[t] = dww[t];
    if (tid < CR) sc[tid] = scl[tid];
    __syncthreads();

    const int g = blockIdx.x * 256 + tid;
    const int b = g >> 12;
    const int p = g & 4095;
    const int h = p >> 6;
    const int w = p & 63;
    const float* zb = z + (((size_t)b * CR) << 12);

    float zc[CR], tw[CR];
    float s1 = 0.f, s2 = 0.f;
    #pragma unroll
    for (int c = 0; c < CR; ++c) {
        const float* zp = zb + ((size_t)c << 12);
        float acc = 0.f;
        float center = 0.f;
        #pragma unroll
        for (int dy = 0; dy < 3; ++dy) {
            const int hy = h + dy - 1;
            const bool rok = ((unsigned)hy) < 64u;
            #pragma unroll
            for (int dx = 0; dx < 3; ++dx) {
                const int wx = w + dx - 1;
                const bool ok = rok && (((unsigned)wx) < 64u);
                float v = 0.f;
                if (ok) v = zp[(hy << 6) + wx];
                if (dy == 1 && dx == 1) center = v;
                acc = fmaf(v, dml[c * 9 + dy * 3 + dx], acc);
            }
        }
        const float t = acc * sc[c];
        zc[c] = center;
        tw[c] = t;
        s1 = fmaf(center, center, s1);
        s2 = fmaf(t, t, s2);
    }
    const float rn1 = 1.0f / fmaxf(sqrtf(s1), 1e-6f);
    const float rn2 = 1.0f / fmaxf(sqrtf(s2), 1e-6f);
    #pragma unroll
    for (int c = 0; c < CR; ++c) { zc[c] *= rn1; tw[c] *= rn2; }

    float* op = out + (((size_t)b * COUT) << 12) + p;
    #pragma unroll
    for (int c = 0; c < CR; ++c) op[(size_t)c << 12] = zc[c];

    float* pp = op + ((size_t)CR << 12);
    #pragma unroll
    for (int i = 0; i < CR; ++i) {
        const float a = zc[i];
        #pragma unroll
        for (int j = i; j < CR; ++j) {
            *pp = a * tw[j];
            pp += HW;
        }
    }
}

extern "C" void kernel_launch(void* const* d_in, const int* in_sizes, int n_in,
                              void* d_out, int out_size, void* d_ws, size_t ws_size,
                              hipStream_t stream) {
    const float* x     = (const float*)d_in[0];
    const float* wr    = (const float*)d_in[1];
    const float* gamma = (const float*)d_in[2];
    const float* beta  = (const float*)d_in[3];
    const float* mean  = (const float*)d_in[4];
    const float* var   = (const float*)d_in[5];
    const float* dww   = (const float*)d_in[6];
    const float* scl   = (const float*)d_in[7];
    float* z = (float*)d_ws;                       // 16*32*4096 fp32 = 8 MB scratch
    float* out = (float*)d_out;

    hipLaunchKernelGGL(k_conv1x1, dim3(256), dim3(256), 0, stream,
                       x, wr, gamma, beta, mean, var, z);
    hipLaunchKernelGGL(k_twist, dim3(256), dim3(256), 0, stream,
                       z, dww, scl, out);
}

// Round 5
// 240.012 us; speedup vs baseline: 1.1502x; 1.1502x over previous
//
#include <hip/hip_runtime.h>
#include <hip/hip_bf16.h>
#include <stdint.h>

#define HW   4096
#define CIN  256
#define CR   32
#define COUT 560   // 32 + 528 pair channels

// Kernel 1: z = relu(bn(conv1x1(x))), fp32. Grid 1024 x 256thr.
// Block covers 64 pixels; thread: 1 pixel (tid&63), 8 out-ch (tid>>6).
// Weights go through the scalar path (wave-uniform og -> s_load / const cache).
__global__ __launch_bounds__(256) void k_conv1x1(
    const float* __restrict__ x,
    const float* __restrict__ wr,
    const float* __restrict__ gamma,
    const float* __restrict__ beta,
    const float* __restrict__ mean,
    const float* __restrict__ var,
    float* __restrict__ z)
{
    const int tid = threadIdx.x;
    const int og  = __builtin_amdgcn_readfirstlane(tid >> 6);  // wave-uniform 0..3
    const int g0  = blockIdx.x * 64 + (tid & 63);              // global pixel
    const int b   = g0 >> 12;
    const int p   = g0 & 4095;

    const float* xb = x + ((((size_t)b) * CIN) << 12) + p;
    const float* wp = wr + (size_t)og * 8 * CIN;               // scalar base

    float acc[8] = {0.f,0.f,0.f,0.f,0.f,0.f,0.f,0.f};

    for (int cc = 0; cc < 16; ++cc) {                          // 16 ic per chunk
        float xv[16];
        #pragma unroll
        for (int k = 0; k < 16; ++k)
            xv[k] = xb[((size_t)(cc * 16 + k)) << 12];
        #pragma unroll
        for (int o = 0; o < 8; ++o) {
            #pragma unroll
            for (int k = 0; k < 16; ++k)
                acc[o] = fmaf(xv[k], wp[o * CIN + cc * 16 + k], acc[o]);
        }
    }

    #pragma unroll
    for (int o = 0; o < 8; ++o) {
        const int oc = og * 8 + o;
        const float inv = gamma[oc] / sqrtf(var[oc] + 1e-5f);
        const float bia = beta[oc] - mean[oc] * inv;
        z[((((size_t)b) * CR + oc) << 12) + p] =
            fmaxf(fmaf(acc[o], inv, bia), 0.f);
    }
}

// Kernel 2: depthwise 3x3 * scale, dual L2-norm, 560 fp32 planes.
// Grid 1024 x 256thr; block = one 64-px row (b, h). Thread: px=tid&63,
// channel-group cg=tid>>6 (8 ch). Norms reduced via LDS; normalized planes
// staged in LDS; phase-2 stores use compile-time plane selection (P&3)==cg.
__global__ __launch_bounds__(256) void k_twist(
    const float* __restrict__ z,
    const float* __restrict__ dww,
    const float* __restrict__ scl,
    float* __restrict__ out)
{
    __shared__ float dml[CR * 9];
    __shared__ float sc[CR];
    __shared__ float ps1[4 * 64];
    __shared__ float ps2[4 * 64];
    __shared__ float znl[CR * 64];   // normalized z   [c][px]
    __shared__ float twl[CR * 64];   // normalized z_tw[c][px]

    const int tid = threadIdx.x;
    for (int t = tid; t < CR * 9; t += 256) dml[t] = dww[t];
    if (tid < CR) sc[tid] = scl[tid];
    __syncthreads();

    const int cg  = __builtin_amdgcn_readfirstlane(tid >> 6);  // 0..3
    const int px  = tid & 63;                                  // w-col
    const int g0  = blockIdx.x * 64;                           // row base
    const int b   = g0 >> 12;
    const int p0  = g0 & 4095;
    const int h   = p0 >> 6;
    const float* zb = z + (((size_t)b * CR) << 12);

    float zc[8], tw[8];
    float s1 = 0.f, s2 = 0.f;
    #pragma unroll
    for (int k = 0; k < 8; ++k) {
        const int c = cg * 8 + k;
        const float* zp = zb + ((size_t)c << 12);
        float acc = 0.f, center = 0.f;
        #pragma unroll
        for (int dy = 0; dy < 3; ++dy) {
            const int hy = h + dy - 1;
            const bool rok = ((unsigned)hy) < 64u;
            #pragma unroll
            for (int dx = 0; dx < 3; ++dx) {
                const int wx = px + dx - 1;
                const bool ok = rok && (((unsigned)wx) < 64u);
                float v = 0.f;
                if (ok) v = zp[(hy << 6) + wx];
                if (dy == 1 && dx == 1) center = v;
                acc = fmaf(v, dml[c * 9 + dy * 3 + dx], acc);
            }
        }
        const float t = acc * sc[c];
        zc[k] = center; tw[k] = t;
        s1 = fmaf(center, center, s1);
        s2 = fmaf(t, t, s2);
    }
    ps1[cg * 64 + px] = s1;
    ps2[cg * 64 + px] = s2;
    __syncthreads();
    const float t1 = ps1[px] + ps1[64 + px] + ps1[128 + px] + ps1[192 + px];
    const float t2 = ps2[px] + ps2[64 + px] + ps2[128 + px] + ps2[192 + px];
    const float rn1 = 1.0f / fmaxf(sqrtf(t1), 1e-6f);
    const float rn2 = 1.0f / fmaxf(sqrtf(t2), 1e-6f);
    #pragma unroll
    for (int k = 0; k < 8; ++k) {
        znl[(cg * 8 + k) * 64 + px] = zc[k] * rn1;
        twl[(cg * 8 + k) * 64 + px] = tw[k] * rn2;
    }
    __syncthreads();

    float* outb = out + (((size_t)b * COUT) << 12) + p0 + px;
    // singles: planes 0..31
    #pragma unroll
    for (int P = 0; P < 32; ++P)
        if ((P & 3) == cg)
            outb[(size_t)P << 12] = znl[P * 64 + px];
    // pairs: planes 32..559, row-major triu (i<=j)
    {
        int P = 32;
        #pragma unroll
        for (int i = 0; i < CR; ++i) {
            #pragma unroll
            for (int j = i; j < CR; ++j) {
                if ((P & 3) == cg)
                    outb[(size_t)P << 12] = znl[i * 64 + px] * twl[j * 64 + px];
                ++P;
            }
        }
    }
}

extern "C" void kernel_launch(void* const* d_in, const int* in_sizes, int n_in,
                              void* d_out, int out_size, void* d_ws, size_t ws_size,
                              hipStream_t stream) {
    const float* x     = (const float*)d_in[0];
    const float* wr    = (const float*)d_in[1];
    const float* gamma = (const float*)d_in[2];
    const float* beta  = (const float*)d_in[3];
    const float* mean  = (const float*)d_in[4];
    const float* var   = (const float*)d_in[5];
    const float* dww   = (const float*)d_in[6];
    const float* scl   = (const float*)d_in[7];
    float* z = (float*)d_ws;                       // 8 MB fp32 scratch
    float* out = (float*)d_out;

    hipLaunchKernelGGL(k_conv1x1, dim3(1024), dim3(256), 0, stream,
                       x, wr, gamma, beta, mean, var, z);
    hipLaunchKernelGGL(k_twist, dim3(1024), dim3(256), 0, stream,
                       z, dww, scl, out);
}